// Round 1
// baseline (8228.627 us; speedup 1.0000x reference)
//
#include <hip/hip_runtime.h>
#include <cmath>

namespace {
constexpr int kB = 32, kT = 128, kD = 512, kH = 1024, kE = 8;
constexpr int kG4 = 4 * kH;   // 4096 gate rows per expert
constexpr int kKV = kH + kD;  // 1536 = concat([h, x]) length

struct Ws {
  float c[kB][kH];  // cell state
  int sel[kB];      // per-batch selected expert for current step
};

__device__ __forceinline__ float sigmoidf_(float v) { return 1.0f / (1.0f + expf(-v)); }
}  // namespace

__global__ __launch_bounds__(256) void k_init(Ws* ws) {
  int tid = blockIdx.x * blockDim.x + threadIdx.x;
  float* c = &ws->c[0][0];
  for (int i = tid; i < kB * kH; i += gridDim.x * blockDim.x) c[i] = 0.0f;
  if (blockIdx.x == 0 && tid < kB) ws->sel[tid] = 0;  // step 0 always expert 0
}

// Selector: one 64-lane block per batch row. logits = [h_{t-1}, x_t] @ sel_W^T + sel_b
__global__ __launch_bounds__(64) void k_select(const float* __restrict__ x,
                                               const float* __restrict__ selW,
                                               const float* __restrict__ selb,
                                               const float* __restrict__ out,
                                               Ws* __restrict__ ws, int t) {
  const int b = blockIdx.x;
  const int lane = threadIdx.x;
  const float* hprev = out + ((size_t)b * kT + (t - 1)) * kH;
  const float* xt = x + ((size_t)b * kT + t) * kD;
  float acc[kE];
#pragma unroll
  for (int e = 0; e < kE; ++e) acc[e] = 0.0f;
  for (int k = lane; k < kKV; k += 64) {
    float v = (k < kH) ? hprev[k] : xt[k - kH];
#pragma unroll
    for (int e = 0; e < kE; ++e) acc[e] += v * selW[e * kKV + k];
  }
#pragma unroll
  for (int e = 0; e < kE; ++e) {
#pragma unroll
    for (int off = 32; off > 0; off >>= 1) acc[e] += __shfl_xor(acc[e], off, 64);
  }
  if (lane == 0) {
    float best = acc[0] + selb[0];
    int bsel = 0;
#pragma unroll
    for (int e = 1; e < kE; ++e) {
      float l = acc[e] + selb[e];
      if (l > best) { best = l; bsel = e; }  // strict > == first-max (jnp.argmax)
    }
    ws->sel[b] = bsel;
  }
}

// Gates + cell update. Grid: (64 unit-blocks, 8 experts), 256 threads (4 waves).
// Block (jb, e) computes gate rows {g*1024 + jb*16 + u : g in 0..3, u in 0..15}
// for every batch row whose selected expert is e, then does the LSTM pointwise
// update for its 16 hidden units and writes h into out[b, t, :].
__global__ __launch_bounds__(256) void k_cell(const float* __restrict__ x,
                                              const float* __restrict__ Wih,
                                              const float* __restrict__ Whh,
                                              const float* __restrict__ bih,
                                              const float* __restrict__ bhh,
                                              float* __restrict__ out,
                                              Ws* __restrict__ ws, int t) {
  const int e = blockIdx.y;
  const int jb = blockIdx.x;
  const int j0 = jb * 16;
  const int tid = threadIdx.x;
  const int wave = tid >> 6;  // == gate index g (0..3 -> i,f,g,o)
  const int lane = tid & 63;

  __shared__ int bl[kB];
  __shared__ int s_cnt;
  __shared__ float v[8][kKV];   // staged [h, x] for up to 8 batch rows (48 KB)
  __shared__ float gl[8][64];   // gates: [bi][g*16+u]

  if (tid == 0) {
    int c = 0;
    for (int b = 0; b < kB; ++b)
      if (ws->sel[b] == e) bl[c++] = b;
    s_cnt = c;
  }
  __syncthreads();
  const int cnt = s_cnt;
  if (cnt == 0) return;

  for (int c0 = 0; c0 < cnt; c0 += 8) {
    const int nb = min(8, cnt - c0);
    // stage v = [h_{t-1} (1024), x_t (512)] per batch row (h==0 at t==0: skip)
    if (t > 0) {
      for (int idx = tid; idx < nb * kKV; idx += 256) {
        int bi = idx / kKV, k = idx - bi * kKV;
        int b = bl[c0 + bi];
        v[bi][k] = (k < kH) ? out[((size_t)b * kT + (t - 1)) * kH + k]
                            : x[((size_t)b * kT + t) * kD + (k - kH)];
      }
    } else {
      for (int idx = tid; idx < nb * kD; idx += 256) {
        int bi = idx / kD, k = idx - bi * kD;
        int b = bl[c0 + bi];
        v[bi][kH + k] = x[((size_t)b * kT + t) * kD + k];
      }
    }
    __syncthreads();

    const int g = wave;
#pragma unroll 1
    for (int up = 0; up < 8; ++up) {  // process rows in pairs: halves LDS reads
      const int u0 = up * 2;
      const int gr0 = g * kH + j0 + u0;  // gr1 = gr0 + 1
      float4 wh0[4], wh1[4], wi0[2], wi1[2];
      if (t > 0) {
        const float4* whp0 = reinterpret_cast<const float4*>(Whh + ((size_t)e * kG4 + gr0) * kH);
        const float4* whp1 = reinterpret_cast<const float4*>(Whh + ((size_t)e * kG4 + gr0 + 1) * kH);
#pragma unroll
        for (int ii = 0; ii < 4; ++ii) {
          wh0[ii] = whp0[lane + 64 * ii];
          wh1[ii] = whp1[lane + 64 * ii];
        }
      }
      {
        const float4* wip0 = reinterpret_cast<const float4*>(Wih + ((size_t)e * kG4 + gr0) * kD);
        const float4* wip1 = reinterpret_cast<const float4*>(Wih + ((size_t)e * kG4 + gr0 + 1) * kD);
#pragma unroll
        for (int ii = 0; ii < 2; ++ii) {
          wi0[ii] = wip0[lane + 64 * ii];
          wi1[ii] = wip1[lane + 64 * ii];
        }
      }

      for (int bi = 0; bi < nb; ++bi) {
        const float4* vh = reinterpret_cast<const float4*>(&v[bi][0]);
        const float4* vx = reinterpret_cast<const float4*>(&v[bi][kH]);
        float a0 = 0.0f, a1 = 0.0f;
        if (t > 0) {
#pragma unroll
          for (int ii = 0; ii < 4; ++ii) {
            float4 bv = vh[lane + 64 * ii];
            a0 += wh0[ii].x * bv.x + wh0[ii].y * bv.y + wh0[ii].z * bv.z + wh0[ii].w * bv.w;
            a1 += wh1[ii].x * bv.x + wh1[ii].y * bv.y + wh1[ii].z * bv.z + wh1[ii].w * bv.w;
          }
        }
#pragma unroll
        for (int ii = 0; ii < 2; ++ii) {
          float4 bv = vx[lane + 64 * ii];
          a0 += wi0[ii].x * bv.x + wi0[ii].y * bv.y + wi0[ii].z * bv.z + wi0[ii].w * bv.w;
          a1 += wi1[ii].x * bv.x + wi1[ii].y * bv.y + wi1[ii].z * bv.z + wi1[ii].w * bv.w;
        }
#pragma unroll
        for (int off = 32; off > 0; off >>= 1) {
          a0 += __shfl_xor(a0, off, 64);
          a1 += __shfl_xor(a1, off, 64);
        }
        if (lane == 0) {
          gl[bi][g * 16 + u0]     = a0 + bih[e * kG4 + gr0]     + bhh[e * kG4 + gr0];
          gl[bi][g * 16 + u0 + 1] = a1 + bih[e * kG4 + gr0 + 1] + bhh[e * kG4 + gr0 + 1];
        }
      }
    }
    __syncthreads();

    if (tid < nb * 16) {
      const int bi = tid >> 4, u = tid & 15;
      const int b = bl[c0 + bi], j = j0 + u;
      const float gi = gl[bi][0 * 16 + u];
      const float gf = gl[bi][1 * 16 + u];
      const float gg = gl[bi][2 * 16 + u];
      const float go = gl[bi][3 * 16 + u];
      const float c_old = (t > 0) ? ws->c[b][j] : 0.0f;
      const float c_new = sigmoidf_(gf) * c_old + sigmoidf_(gi) * tanhf(gg);
      const float h_new = sigmoidf_(go) * tanhf(c_new);
      ws->c[b][j] = c_new;
      out[((size_t)b * kT + t) * kH + j] = h_new;
    }
    __syncthreads();  // protect v/gl before next chunk
  }
}

extern "C" void kernel_launch(void* const* d_in, const int* in_sizes, int n_in,
                              void* d_out, int out_size, void* d_ws, size_t ws_size,
                              hipStream_t stream) {
  const float* x    = (const float*)d_in[0];
  const float* Wih  = (const float*)d_in[1];
  const float* Whh  = (const float*)d_in[2];
  const float* bih  = (const float*)d_in[3];
  const float* bhh  = (const float*)d_in[4];
  const float* selW = (const float*)d_in[5];
  const float* selb = (const float*)d_in[6];
  float* out = (float*)d_out;
  Ws* ws = (Ws*)d_ws;

  k_init<<<dim3(32), dim3(256), 0, stream>>>(ws);
  for (int t = 0; t < kT; ++t) {
    if (t > 0) {
      k_select<<<dim3(kB), dim3(64), 0, stream>>>(x, selW, selb, out, ws, t);
    }
    k_cell<<<dim3(64, kE), dim3(256), 0, stream>>>(x, Wih, Whh, bih, bhh, out, ws, t);
  }
}